// Round 1
// baseline (425.767 us; speedup 1.0000x reference)
//
#include <hip/hip_runtime.h>
#include <stdint.h>

#pragma clang fp contract(off)

#define NH 192
#define NW 192
#define NK 9
#define NPB (NH * NW * NK)   // 331776 anchors per batch
#define PRE_NMS 2048
#define CAP 4096             // compacted-candidate capacity per batch
#define MOS 100
#define SCORE_T 0.9f
#define IOU_T 0.9f

// ---------------- workspace layout (per launch, zeroed by zero_meta) ----------
// hist : B*256 int
// cnt  : B int
// thr  : B int
// keys : B*CAP u64   (not zeroed; guarded by cnt)

__global__ void zero_meta(int* __restrict__ meta, int n) {
    int i = blockIdx.x * blockDim.x + threadIdx.x;
    if (i < n) meta[i] = 0;
}

// Histogram of score-bit bucket (bits>>16)&0xFF for scores > SCORE_T.
// grid: (NPB/4096, B), block 256, 16 elems/thread.
__global__ void hist_kernel(const float* __restrict__ scores, int* __restrict__ hist) {
    __shared__ int lh[256];
    const int t = threadIdx.x;
    lh[t] = 0;
    __syncthreads();
    const int b = blockIdx.y;
    const float* sp = scores + (size_t)b * NPB + (size_t)blockIdx.x * 4096;
#pragma unroll
    for (int i = 0; i < 16; ++i) {
        float s = sp[t + i * 256];
        if (s > SCORE_T) atomicAdd(&lh[(__float_as_uint(s) >> 16) & 0xFF], 1);
    }
    __syncthreads();
    if (lh[t] != 0) atomicAdd(&hist[b * 256 + t], lh[t]);
}

// Per batch: find bucket where descending cumulative count crosses PRE_NMS.
__global__ void thresh_kernel(const int* __restrict__ hist, int* __restrict__ thr, int B) {
    int b = blockIdx.x * blockDim.x + threadIdx.x;
    if (b < B) {
        int cum = 0, tv = 0;
        for (int v = 255; v >= 0; --v) {
            cum += hist[b * 256 + v];
            if (cum >= PRE_NMS) { tv = v; break; }
        }
        thr[b] = tv;
    }
}

// Compact all candidates with score > SCORE_T and bucket >= thr[b] into
// 64-bit keys (score_bits<<32)|~idx. grid: (NPB/4096, B), block 256.
__global__ void compact_kernel(const float* __restrict__ scores,
                               const int* __restrict__ thr,
                               int* __restrict__ cnt,
                               unsigned long long* __restrict__ keys) {
    __shared__ unsigned long long stage[4096];
    __shared__ int lcount, lbase;
    const int t = threadIdx.x;
    if (t == 0) lcount = 0;
    __syncthreads();
    const int b = blockIdx.y;
    const int th = thr[b];
    const int base_i = blockIdx.x * 4096;
    const float* sp = scores + (size_t)b * NPB + base_i;
#pragma unroll
    for (int i = 0; i < 16; ++i) {
        int li = t + i * 256;
        float s = sp[li];
        unsigned int bits = __float_as_uint(s);
        if (s > SCORE_T && (int)((bits >> 16) & 0xFF) >= th) {
            int p = atomicAdd(&lcount, 1);
            unsigned int idx = (unsigned int)(base_i + li);
            stage[p] = ((unsigned long long)bits << 32) | (unsigned long long)(~idx);
        }
    }
    __syncthreads();
    if (t == 0) lbase = atomicAdd(&cnt[b], lcount);
    __syncthreads();
    const int nb = lcount, gb = lbase;
    unsigned long long* kb = keys + (size_t)b * CAP;
    for (int i = t; i < nb; i += 256) {
        int gp = gb + i;
        if (gp < CAP) kb[gp] = stage[i];
    }
}

// One block per batch: bitonic sort CAP keys (desc) in LDS, decode top
// PRE_NMS boxes, sequential greedy NMS (100 steps), write out[b][step][4].
__global__ __launch_bounds__(1024) void nms_kernel(
        const float* __restrict__ deltas, const float* __restrict__ anchors,
        const int* __restrict__ cnt, const unsigned long long* __restrict__ keys,
        float* __restrict__ out) {
    // smem layout: keys [0,32768); boxes alias [16384,49152) — boxes[j] only
    // overwrites key slots >= 2048, which are dead after the sort.
    __shared__ __align__(16) unsigned char smem[49152];
    unsigned long long* key_s = (unsigned long long*)smem;
    float* boxes = (float*)(smem + 16384);   // boxes[PRE_NMS][4]
    __shared__ unsigned char sup[PRE_NMS];
    __shared__ int s_head, s_pick;

    const int t = threadIdx.x;
    const int b = blockIdx.x;
    const int nc = min(cnt[b], CAP);
    const unsigned long long* kb = keys + (size_t)b * CAP;
    for (int i = t; i < CAP; i += 1024) key_s[i] = (i < nc) ? kb[i] : 0ULL;
    __syncthreads();

    // Bitonic sort, descending. Padding keys (0) sink to the tail.
    for (int k = 2; k <= CAP; k <<= 1) {
        for (int j = k >> 1; j > 0; j >>= 1) {
#pragma unroll
            for (int p = 0; p < CAP / 1024; ++p) {
                int i = t + p * 1024;
                int ix = i ^ j;
                if (ix > i) {
                    unsigned long long a = key_s[i], c = key_s[ix];
                    bool up = ((i & k) == 0);
                    if (up ? (a < c) : (a > c)) { key_s[i] = c; key_s[ix] = a; }
                }
            }
            __syncthreads();
        }
    }

    // Decode top PRE_NMS candidates into LDS boxes; mark invalid as suppressed.
    for (int jj = t; jj < PRE_NMS; jj += 1024) {
        unsigned long long key = key_s[jj];
        unsigned int hi = (unsigned int)(key >> 32);
        float4 bx = make_float4(0.f, 0.f, 0.f, 0.f);
        unsigned char sp_ = 1;
        if (hi > 0x3F666666u) {   // score > 0.9f
            unsigned int idx = ~(unsigned int)(key & 0xFFFFFFFFu);
            const float4 a = ((const float4*)anchors)[idx];   // [xmin,xmax,ymin,ymax]
            int hw = (int)idx / NK;
            int kk = (int)idx - hw * NK;
            const float* dp = deltas + (size_t)b * (NPB * 4) + (size_t)hw * (NK * 4) + kk * 4;
            float tx = dp[0], ty = dp[1], tw = dp[2], th2 = dp[3];
            float xa = (a.x + a.y) * 0.5f;
            float ya = (a.z + a.w) * 0.5f;
            float wa = a.y - a.x;
            float ha = a.w - a.z;
            float x = tx * wa + xa;
            float y = ty * ha + ya;
            float w = expf(tw) * wa;
            float h = expf(th2) * ha;
            float xmin = fmaxf(x - w * 0.5f, 0.f);
            float xmax = fminf(x + w * 0.5f, 1.f);
            float ymin = fmaxf(y - h * 0.5f, 0.f);
            float ymax = fminf(y + h * 0.5f, 1.f);
            bx = make_float4(ymax, xmin, ymin, xmax);
            sp_ = 0;
        }
        ((float4*)boxes)[jj] = bx;
        sup[jj] = sp_;
    }
    if (t == 0) s_head = 0;
    __syncthreads();

    float4* out4 = (float4*)out + (size_t)b * MOS;
    for (int step = 0; step < MOS; ++step) {
        if (t == 0) {
            int h = s_head;
            while (h < PRE_NMS && sup[h]) ++h;
            if (h < PRE_NMS) {
                s_pick = h;
                sup[h] = 1;
                s_head = h + 1;
                out4[step] = ((float4*)boxes)[h];
            } else {
                s_pick = -1;
                out4[step] = make_float4(0.f, 0.f, 0.f, 0.f);
            }
        }
        __syncthreads();
        const int p = s_pick;
        if (p >= 0) {
            float py2 = boxes[p * 4 + 0], px1 = boxes[p * 4 + 1];
            float py1 = boxes[p * 4 + 2], px2 = boxes[p * 4 + 3];
            float area_p = fmaxf(py2 - py1, 0.f) * fmaxf(px2 - px1, 0.f);
            for (int jj = t; jj < PRE_NMS; jj += 1024) {
                if (!sup[jj]) {
                    float y2 = boxes[jj * 4 + 0], x1 = boxes[jj * 4 + 1];
                    float y1 = boxes[jj * 4 + 2], x2 = boxes[jj * 4 + 3];
                    float area_b = fmaxf(y2 - y1, 0.f) * fmaxf(x2 - x1, 0.f);
                    float ih = fmaxf(fminf(py2, y2) - fmaxf(py1, y1), 0.f);
                    float iw = fmaxf(fminf(px2, x2) - fmaxf(px1, x1), 0.f);
                    float inter = ih * iw;
                    float iou = inter / (area_p + area_b - inter + 1e-9f);
                    if (iou > IOU_T) sup[jj] = 1;
                }
            }
        }
        __syncthreads();
    }
}

extern "C" void kernel_launch(void* const* d_in, const int* in_sizes, int n_in,
                              void* d_out, int out_size, void* d_ws, size_t ws_size,
                              hipStream_t stream) {
    const float* score_map = (const float*)d_in[0];
    const float* delta_map = (const float*)d_in[1];
    const float* anchors   = (const float*)d_in[2];
    float* out = (float*)d_out;
    const int B = in_sizes[0] / NPB;   // 32

    char* ws = (char*)d_ws;
    int* hist = (int*)ws;                                    // B*256 ints
    int* cnt  = (int*)(ws + (size_t)B * 256 * 4);            // B ints
    int* thr  = (int*)(ws + (size_t)B * 256 * 4 + B * 4);    // B ints
    unsigned long long* keys =
        (unsigned long long*)(ws + (size_t)B * 256 * 4 + 2 * (size_t)B * 4); // B*CAP u64

    const int meta_n = B * 256 + 2 * B;
    zero_meta<<<(meta_n + 255) / 256, 256, 0, stream>>>(hist, meta_n);
    hist_kernel<<<dim3(NPB / 4096, B), 256, 0, stream>>>(score_map, hist);
    thresh_kernel<<<1, 256, 0, stream>>>(hist, thr, B);
    compact_kernel<<<dim3(NPB / 4096, B), 256, 0, stream>>>(score_map, thr, cnt, keys);
    nms_kernel<<<B, 1024, 0, stream>>>(delta_map, anchors, cnt, keys, out);
}

// Round 2
// 350.014 us; speedup vs baseline: 1.2164x; 1.2164x over previous
//
#include <hip/hip_runtime.h>
#include <stdint.h>

#pragma clang fp contract(off)

typedef unsigned long long u64;
typedef unsigned int u32;

#define NH 192
#define NW 192
#define NK 9
#define NPB (NH * NW * NK)   // 331776 anchors per batch
#define PRE_NMS 2048
#define CAP 4096             // compacted-candidate capacity per batch
#define MOS 100
#define SCORE_T_BITS 0x3F666666u   // float bits of 0.9f (all scores in [0,1) -> positive)
#define IOU_T 0.9f

// ws layout: hist B*256 int | cnt B int | bound B u32 | keys B*CAP u64

__global__ void zero_meta(int* __restrict__ meta, int n) {
    int i = blockIdx.x * blockDim.x + threadIdx.x;
    if (i < n) meta[i] = 0;
}

// Histogram of (bits>>16)&0xFF for scores with bits > SCORE_T_BITS.
// grid (81, B), block 256; each thread 4x uint4 = 16 scores.
__global__ void hist_kernel(const uint4* __restrict__ scores, int* __restrict__ hist) {
    __shared__ int lh[256];
    const int t = threadIdx.x;
    lh[t] = 0;
    __syncthreads();
    const int b = blockIdx.y;
    const uint4* sp = scores + (size_t)b * (NPB / 4) + (size_t)blockIdx.x * 1024;
#pragma unroll
    for (int i = 0; i < 4; ++i) {
        uint4 v = sp[t + i * 256];
        if (v.x > SCORE_T_BITS) atomicAdd(&lh[(v.x >> 16) & 0xFF], 1);
        if (v.y > SCORE_T_BITS) atomicAdd(&lh[(v.y >> 16) & 0xFF], 1);
        if (v.z > SCORE_T_BITS) atomicAdd(&lh[(v.z >> 16) & 0xFF], 1);
        if (v.w > SCORE_T_BITS) atomicAdd(&lh[(v.w >> 16) & 0xFF], 1);
    }
    __syncthreads();
    if (lh[t] != 0) atomicAdd(&hist[b * 256 + t], lh[t]);
}

// Per batch: bucket where descending cumulative count crosses PRE_NMS, folded
// with the score>0.9 test into a single uint lower bound on score bits.
__global__ void thresh_kernel(const int* __restrict__ hist, u32* __restrict__ bound, int B) {
    int b = blockIdx.x * blockDim.x + threadIdx.x;
    if (b < B) {
        int cum = 0, tv = 0;
        for (int v = 255; v >= 0; --v) {
            cum += hist[b * 256 + v];
            if (cum >= PRE_NMS) { tv = v; break; }
        }
        u32 bd = ((u32)(0x3F00 + tv)) << 16;       // bucket >= tv  (exp byte is 0x3F)
        if (bd < SCORE_T_BITS + 1) bd = SCORE_T_BITS + 1;  // and score > 0.9
        bound[b] = bd;
    }
}

// Compact candidates with bits >= bound into keys (score_bits<<32)|~idx.
// grid (81, B), block 256.
__global__ void compact_kernel(const uint4* __restrict__ scores,
                               const u32* __restrict__ bound,
                               int* __restrict__ cnt,
                               u64* __restrict__ keys) {
    __shared__ u64 stage[4096];
    __shared__ int lcount, lbase;
    const int t = threadIdx.x;
    if (t == 0) lcount = 0;
    __syncthreads();
    const int b = blockIdx.y;
    const u32 bd = bound[b];
    const int base_i = blockIdx.x * 4096;
    const uint4* sp = scores + (size_t)b * (NPB / 4) + (size_t)blockIdx.x * 1024;
#pragma unroll
    for (int i = 0; i < 4; ++i) {
        uint4 v = sp[t + i * 256];
        int ei = base_i + (t + i * 256) * 4;
        u32 uu[4] = {v.x, v.y, v.z, v.w};
#pragma unroll
        for (int c = 0; c < 4; ++c) {
            if (uu[c] >= bd) {
                int p = atomicAdd(&lcount, 1);
                u32 idx = (u32)(ei + c);
                stage[p] = ((u64)uu[c] << 32) | (u64)(~idx);
            }
        }
    }
    __syncthreads();
    if (t == 0) lbase = atomicAdd(&cnt[b], lcount);
    __syncthreads();
    const int nb = lcount, gb = lbase;
    u64* kb = keys + (size_t)b * CAP;
    for (int i = t; i < nb; i += 256) {
        int gp = gb + i;
        if (gp < CAP) kb[gp] = stage[i];
    }
}

// One block per batch: bitonic sort CAP keys desc (register j=1,2 levels),
// decode top PRE_NMS boxes into LDS, then wave 0 runs candidate-form greedy
// NMS (pick j iff IoU vs all earlier picks <= T) with picks in registers.
__global__ __launch_bounds__(1024) void sort_nms_kernel(
        const float* __restrict__ deltas, const float* __restrict__ anchors,
        const int* __restrict__ cnt, const u64* __restrict__ keys,
        float* __restrict__ out) {
    __shared__ __align__(16) u64 key_s[CAP];        // 32 KB
    __shared__ __align__(16) float4 boxes[PRE_NMS]; // 32 KB
    const int t = threadIdx.x;
    const int b = blockIdx.x;
    const int nc = min(cnt[b], CAP);
    const u64* kb = keys + (size_t)b * CAP;
#pragma unroll
    for (int p = 0; p < 4; ++p) {
        int i = t + p * 1024;
        key_s[i] = (i < nc) ? kb[i] : 0ULL;
    }
    __syncthreads();

    // Bitonic sort, descending; unique nonzero keys, zero padding sinks to tail.
    for (int k = 2; k <= CAP; k <<= 1) {
        for (int j = k >> 1; j >= 4; j >>= 1) {
#pragma unroll
            for (int p = 0; p < 4; ++p) {
                int i = t + p * 1024;
                int ix = i ^ j;
                if (ix > i) {
                    u64 a = key_s[i], c = key_s[ix];
                    bool up = ((i & k) == 0);
                    if (up ? (a < c) : (a > c)) { key_s[i] = c; key_s[ix] = a; }
                }
            }
            __syncthreads();
        }
        // j = 2,1 in registers: thread owns elements [4t, 4t+3]
        {
            const int base = t * 4;
            u64 e0 = key_s[base + 0], e1 = key_s[base + 1];
            u64 e2 = key_s[base + 2], e3 = key_s[base + 3];
            if (k == 2) {
                // pair (0,1): i&2==0 -> up; pair (2,3): down
                if (e0 < e1) { u64 x = e0; e0 = e1; e1 = x; }
                if (e2 > e3) { u64 x = e2; e2 = e3; e3 = x; }
            } else {
                bool up = ((base & k) == 0);   // constant over the 4-block for k>=4
#define CE(a, b) { if (up ? (a < b) : (a > b)) { u64 x = a; a = b; b = x; } }
                CE(e0, e2) CE(e1, e3) CE(e0, e1) CE(e2, e3)
#undef CE
            }
            key_s[base + 0] = e0; key_s[base + 1] = e1;
            key_s[base + 2] = e2; key_s[base + 3] = e3;
            __syncthreads();
        }
    }

    // Decode top PRE_NMS candidates into LDS boxes [ymax,xmin,ymin,xmax].
#pragma unroll
    for (int p = 0; p < 2; ++p) {
        int jj = t + p * 1024;
        u64 key = key_s[jj];
        u32 hi = (u32)(key >> 32);
        float4 bx = make_float4(0.f, 0.f, 0.f, 0.f);
        if (hi > SCORE_T_BITS) {
            u32 idx = ~(u32)(key & 0xFFFFFFFFu);
            float4 a = ((const float4*)anchors)[idx];   // [xmin,xmax,ymin,ymax]
            float4 d = ((const float4*)deltas)[(size_t)b * NPB + idx]; // [tx,ty,tw,th]
            float xa = (a.x + a.y) * 0.5f;
            float ya = (a.z + a.w) * 0.5f;
            float wa = a.y - a.x;
            float ha = a.w - a.z;
            float x = d.x * wa + xa;
            float y = d.y * ha + ya;
            float w = expf(d.z) * wa;
            float h = expf(d.w) * ha;
            bx.x = fminf(y + h * 0.5f, 1.f);   // ymax
            bx.y = fmaxf(x - w * 0.5f, 0.f);   // xmin
            bx.z = fmaxf(y - h * 0.5f, 0.f);   // ymin
            bx.w = fminf(x + w * 0.5f, 1.f);   // xmax
        }
        boxes[jj] = bx;
    }
    __syncthreads();

    if (t >= 64) return;   // wave 0 finishes NMS alone; no more barriers
    const int lane = t;
    const int nvalid = min(nc, PRE_NMS);
    float4* out4 = (float4*)out + (size_t)b * MOS;

    float4 pb0, pb1;           // pick slots: pick #lane, pick #(64+lane)
    float pa0 = 0.f, pa1 = 0.f;
    pb0 = pb1 = make_float4(0.f, 0.f, 0.f, 0.f);
    int np = 0;

    float4 nxt = boxes[0];     // LDS same-address broadcast, prefetched
    for (int j = 0; j < nvalid; ++j) {
        float4 cb = nxt;
        nxt = boxes[(j + 1 < nvalid) ? (j + 1) : j];
        float areab = fmaxf(cb.x - cb.z, 0.f) * fmaxf(cb.w - cb.y, 0.f);
        bool sup = false;
        if (lane < np) {
            float ih = fmaxf(fminf(pb0.x, cb.x) - fmaxf(pb0.z, cb.z), 0.f);
            float iw = fmaxf(fminf(pb0.w, cb.w) - fmaxf(pb0.y, cb.y), 0.f);
            float inter = ih * iw;
            sup = inter / (pa0 + areab - inter + 1e-9f) > IOU_T;
        }
        if (lane + 64 < np) {
            float ih = fmaxf(fminf(pb1.x, cb.x) - fmaxf(pb1.z, cb.z), 0.f);
            float iw = fmaxf(fminf(pb1.w, cb.w) - fmaxf(pb1.y, cb.y), 0.f);
            float inter = ih * iw;
            sup = sup || (inter / (pa1 + areab - inter + 1e-9f) > IOU_T);
        }
        if (!__any(sup)) {
            if (lane == (np & 63)) {
                if (np < 64) { pb0 = cb; pa0 = areab; }
                else         { pb1 = cb; pa1 = areab; }
                out4[np] = cb;
            }
            ++np;
            if (np == MOS) break;
        }
    }
    for (int i = np + lane; i < MOS; i += 64)
        out4[i] = make_float4(0.f, 0.f, 0.f, 0.f);
}

extern "C" void kernel_launch(void* const* d_in, const int* in_sizes, int n_in,
                              void* d_out, int out_size, void* d_ws, size_t ws_size,
                              hipStream_t stream) {
    const float* score_map = (const float*)d_in[0];
    const float* delta_map = (const float*)d_in[1];
    const float* anchors   = (const float*)d_in[2];
    float* out = (float*)d_out;
    const int B = in_sizes[0] / NPB;   // 32

    char* ws = (char*)d_ws;
    int* hist  = (int*)ws;                                        // B*256 ints
    int* cnt   = (int*)(ws + (size_t)B * 256 * 4);                // B ints
    u32* bound = (u32*)(ws + (size_t)B * 256 * 4 + (size_t)B * 4);// B u32
    u64* keys  = (u64*)(ws + (size_t)B * 256 * 4 + 2 * (size_t)B * 4); // B*CAP u64

    const int meta_n = B * 256 + B;   // hist + cnt
    zero_meta<<<(meta_n + 255) / 256, 256, 0, stream>>>(hist, meta_n);
    hist_kernel<<<dim3(NPB / 4096, B), 256, 0, stream>>>((const uint4*)score_map, hist);
    thresh_kernel<<<1, 256, 0, stream>>>(hist, bound, B);
    compact_kernel<<<dim3(NPB / 4096, B), 256, 0, stream>>>((const uint4*)score_map, bound, cnt, keys);
    sort_nms_kernel<<<B, 1024, 0, stream>>>(delta_map, anchors, cnt, keys, out);
}